// Round 2
// baseline (3324.608 us; speedup 1.0000x reference)
//
#include <hip/hip_runtime.h>

// FeatureEnhance: 4-stream PAM + CAM + shared 3x3 conv.
// S=4 streams, B=2, C=256, CQ=32, H=W=64, N=HW=4096.
// Round 1: fix enum collision with math.h M_E macro (GM_ prefix).
// ws requirement: ~145.3 MB (Q,K,V,E,stats,G,attsum,Y).

#define HW 4096

struct XPtrs { const float* p[4]; };

enum { GM_PROJ = 0, GM_E = 1, GM_GRAM = 2, GM_PV = 3, GM_CAM = 4, GM_CONV = 5 };

// Generic 64x64-tile f32 GEMM, 256 threads, BK=16, 4x4 micro-tile.
// C[m,n] = sum_k A[m,k] * B[k,n], with mode-specific operand sourcing:
//   GM_PROJ: A = W (NN), B = X (NN via xs ptrs), epilogue + bias[m]
//   GM_E:    A = Q^T (As[k][i] = Q[k][i]), B = K (NN); writes energy E[n_q][m_k]
//   GM_GRAM: A = X (NN), B = X^T (NT); writes G[c][d]
//   GM_PV:   A = V (NN), B[k][n] = exp(E[n][k]-rmax[n])*rsinv[n] (NT+transform);
//            epilogue scales by gamma_pam, writes Y
//   GM_CAM:  A = attsum[b] (NN), B = X (NN); epilogue Y += g_cam*acc + 5*X
//   GM_CONV: A = Wd [256][2304] (NN), B = im2col(Y) on the fly; + bias, -> d_out
template<int MODE>
__global__ __launch_bounds__(256)
void gemm_k(const float* __restrict__ A, const float* __restrict__ Bp,
            float* __restrict__ Cp,
            const float* __restrict__ bias,
            const float* __restrict__ rmaxp, const float* __restrict__ rsinvp,
            const float* __restrict__ gscale, XPtrs xs,
            int M, int K, int lda, int ldb, int ldc,
            long aBatch, long bBatch, long cBatch)
{
    const int bx = blockIdx.x, by = blockIdx.y, bz = blockIdx.z;
    const int n0 = bx * 64, m0 = by * 64;
    const int t  = threadIdx.x;
    const int tm = t >> 4, tn = t & 15;

    const float* xb = nullptr;
    if constexpr (MODE == GM_PROJ || MODE == GM_GRAM || MODE == GM_CAM)
        xb = xs.p[bz >> 1] + (size_t)(bz & 1) * (256 * HW);

    const float* Ab;
    if constexpr (MODE == GM_GRAM)      Ab = xb;
    else if constexpr (MODE == GM_CAM)  Ab = A + (size_t)(bz & 1) * aBatch;
    else                                Ab = A + (size_t)bz * aBatch;

    const float* Bb;
    if constexpr (MODE == GM_PROJ || MODE == GM_GRAM || MODE == GM_CAM) Bb = xb;
    else Bb = Bp + (size_t)bz * bBatch;

    float* Cb = Cp + (size_t)bz * cBatch;

    __shared__ float As[16][68];   // As[k][m], padded stride 68 (bank-safe, 16B-aligned)
    __shared__ float Bs[16][68];   // Bs[k][n]

    float acc[4][4] = {};

    for (int kb = 0; kb < K; kb += 16) {
        // ---- load A tile ----
        if constexpr (MODE == GM_E) {
            // As[k][i] = Q[kb+k][m0+i]  (A^T access, coalesced along i)
            const int k = t >> 4, i0 = (t & 15) * 4;
            float4 v = *(const float4*)(Ab + (size_t)(kb + k) * lda + (m0 + i0));
            *(float4*)&As[k][i0] = v;
        } else {
            const int m = t >> 2, k0 = (t & 3) * 4;
            float4 v = make_float4(0.f, 0.f, 0.f, 0.f);
            if (m0 + m < M)
                v = *(const float4*)(Ab + (size_t)(m0 + m) * lda + (kb + k0));
            As[k0 + 0][m] = v.x;
            As[k0 + 1][m] = v.y;
            As[k0 + 2][m] = v.z;
            As[k0 + 3][m] = v.w;
        }
        // ---- load B tile ----
        if constexpr (MODE == GM_PROJ || MODE == GM_CAM || MODE == GM_E) {
            // NN: Bs[k][n] = B[kb+k][n0+n]
            const int k = t >> 4, c0 = (t & 15) * 4;
            float4 v = *(const float4*)(Bb + (size_t)(kb + k) * ldb + (n0 + c0));
            *(float4*)&Bs[k][c0] = v;
        } else if constexpr (MODE == GM_GRAM || MODE == GM_PV) {
            // NT: Bs[k][n] = Bt[n0+n][kb+k]   (+ softmax transform for PV)
            const int n = t >> 2, k0 = (t & 3) * 4;
            float4 v = *(const float4*)(Bb + (size_t)(n0 + n) * ldb + (kb + k0));
            if constexpr (MODE == GM_PV) {
                const float mx = rmaxp[n0 + n], ri = rsinvp[n0 + n];
                v.x = __expf(v.x - mx) * ri;
                v.y = __expf(v.y - mx) * ri;
                v.z = __expf(v.z - mx) * ri;
                v.w = __expf(v.w - mx) * ri;
            }
            Bs[k0 + 0][n] = v.x;
            Bs[k0 + 1][n] = v.y;
            Bs[k0 + 2][n] = v.z;
            Bs[k0 + 3][n] = v.w;
        } else { // GM_CONV: im2col element B[k][n] = y[ic][h+dh][w+dw] with zero pad
            const int k = t >> 4, c0 = (t & 15) * 4;
            const int kk = kb + k;
            const int ic = kk / 9;
            const int r  = kk - ic * 9;
            const int dh = r / 3 - 1;
            const int dw = r - (r / 3) * 3 - 1;
            const int h  = n0 >> 6;           // BN=64 == W, so each n-tile is one row
            const int ih = h + dh;
            #pragma unroll
            for (int i = 0; i < 4; ++i) {
                const int w = c0 + i, iw = w + dw;
                float v = 0.f;
                if (ih >= 0 && ih < 64 && iw >= 0 && iw < 64)
                    v = Bb[(size_t)ic * HW + ih * 64 + iw];
                Bs[k][w] = v;
            }
        }
        __syncthreads();

        #pragma unroll
        for (int k = 0; k < 16; ++k) {
            const float4 a = *(const float4*)&As[k][tm * 4];
            const float4 b = *(const float4*)&Bs[k][tn * 4];
            acc[0][0] += a.x * b.x; acc[0][1] += a.x * b.y; acc[0][2] += a.x * b.z; acc[0][3] += a.x * b.w;
            acc[1][0] += a.y * b.x; acc[1][1] += a.y * b.y; acc[1][2] += a.y * b.z; acc[1][3] += a.y * b.w;
            acc[2][0] += a.z * b.x; acc[2][1] += a.z * b.y; acc[2][2] += a.z * b.z; acc[2][3] += a.z * b.w;
            acc[3][0] += a.w * b.x; acc[3][1] += a.w * b.y; acc[3][2] += a.w * b.z; acc[3][3] += a.w * b.w;
        }
        __syncthreads();
    }

    float g = 0.f;
    if constexpr (MODE == GM_PV || MODE == GM_CAM) g = gscale[0];

    #pragma unroll
    for (int i = 0; i < 4; ++i) {
        const int m = m0 + tm * 4 + i;
        if (m < M) {
            const size_t off = (size_t)m * ldc + (n0 + tn * 4);
            float4 r = make_float4(acc[i][0], acc[i][1], acc[i][2], acc[i][3]);
            if constexpr (MODE == GM_PROJ || MODE == GM_CONV) {
                const float bi = bias[m];
                r.x += bi; r.y += bi; r.z += bi; r.w += bi;
            }
            if constexpr (MODE == GM_PV) {
                r.x *= g; r.y *= g; r.z *= g; r.w *= g;
            }
            if constexpr (MODE == GM_CAM) {
                const float4 yv = *(const float4*)(Cb + off);
                const float4 xv = *(const float4*)(xb + (size_t)m * HW + (n0 + tn * 4));
                r.x = yv.x + g * r.x + 5.f * xv.x;
                r.y = yv.y + g * r.y + 5.f * xv.y;
                r.z = yv.z + g * r.z + 5.f * xv.z;
                r.w = yv.w + g * r.w + 5.f * xv.w;
            }
            *(float4*)(Cb + off) = r;
        }
    }
}

// Per-row max and 1/sum(exp(e-max)) over E rows of length 4096.
__global__ __launch_bounds__(256)
void rowstats_k(const float* __restrict__ E, float* __restrict__ rmax,
                float* __restrict__ rsinv)
{
    __shared__ float red[4];
    __shared__ float bmax;
    const int t = threadIdx.x;
    const float* row = E + (size_t)blockIdx.x * HW;

    float m = -3.4e38f;
    for (int i = t * 4; i < HW; i += 1024) {
        const float4 v = *(const float4*)(row + i);
        m = fmaxf(fmaxf(fmaxf(m, v.x), v.y), fmaxf(v.z, v.w));
    }
    for (int o = 32; o; o >>= 1) m = fmaxf(m, __shfl_down(m, o));
    if ((t & 63) == 0) red[t >> 6] = m;
    __syncthreads();
    if (t == 0) bmax = fmaxf(fmaxf(red[0], red[1]), fmaxf(red[2], red[3]));
    __syncthreads();
    m = bmax;

    float s = 0.f;
    for (int i = t * 4; i < HW; i += 1024) {
        const float4 v = *(const float4*)(row + i);
        s += __expf(v.x - m) + __expf(v.y - m) + __expf(v.z - m) + __expf(v.w - m);
    }
    for (int o = 32; o; o >>= 1) s += __shfl_down(s, o);
    if ((t & 63) == 0) red[t >> 6] = s;
    __syncthreads();
    if (t == 0) {
        rmax[blockIdx.x]  = m;
        rsinv[blockIdx.x] = 1.0f / (red[0] + red[1] + red[2] + red[3]);
    }
}

// CAM softmax: att[c,d] = softmax_d(rowmax - e) = exp(rowmin - e)/sum;
// accumulates over the 4 streams into attsum[b][c][d].
__global__ __launch_bounds__(256)
void cam_softmax_k(const float* __restrict__ G, float* __restrict__ attsum)
{
    __shared__ float rmn[4], rsm[4];
    const int c = blockIdx.x, b = blockIdx.y;
    const int d = threadIdx.x;
    float acc = 0.f;
    for (int s = 0; s < 4; ++s) {
        const float* row = G + (((size_t)(s * 2 + b)) * 256 + c) * 256;
        const float e = row[d];
        float mn = e;
        for (int o = 32; o; o >>= 1) mn = fminf(mn, __shfl_down(mn, o));
        if ((d & 63) == 0) rmn[d >> 6] = mn;
        __syncthreads();
        mn = fminf(fminf(rmn[0], rmn[1]), fminf(rmn[2], rmn[3]));
        const float ex = __expf(mn - e);
        float sm = ex;
        for (int o = 32; o; o >>= 1) sm += __shfl_down(sm, o);
        if ((d & 63) == 0) rsm[d >> 6] = sm;
        __syncthreads();
        sm = rsm[0] + rsm[1] + rsm[2] + rsm[3];
        acc += ex * (1.0f / sm);
        __syncthreads();   // protect rmn/rsm before next stream iteration
    }
    attsum[((size_t)b * 256 + c) * 256 + d] = acc;
}

extern "C" void kernel_launch(void* const* d_in, const int* in_sizes, int n_in,
                              void* d_out, int out_size, void* d_ws, size_t ws_size,
                              hipStream_t stream)
{
    XPtrs xs;
    xs.p[0] = (const float*)d_in[0];
    xs.p[1] = (const float*)d_in[1];
    xs.p[2] = (const float*)d_in[2];
    xs.p[3] = (const float*)d_in[3];
    const float* Wq = (const float*)d_in[4];
    const float* bq = (const float*)d_in[5];
    const float* Wk = (const float*)d_in[6];
    const float* bk = (const float*)d_in[7];
    const float* Wv = (const float*)d_in[8];
    const float* bv = (const float*)d_in[9];
    const float* gp = (const float*)d_in[10];   // gamma_pam
    const float* gc = (const float*)d_in[11];   // gamma_cam
    const float* Wd = (const float*)d_in[12];
    const float* bd = (const float*)d_in[13];

    float* ws  = (float*)d_ws;
    float* Q   = ws;                    // 8 * 32  * 4096 = 1,048,576
    float* Km  = Q   + 1048576;         // 1,048,576
    float* V   = Km  + 1048576;         // 8 * 256 * 4096 = 8,388,608
    float* E   = V   + 8388608;         // 4096 * 4096    = 16,777,216 (reused per sb)
    float* rmx = E   + 16777216;        // 4096
    float* rsi = rmx + 4096;            // 4096
    float* G   = rsi + 4096;            // 8 * 256 * 256  = 524,288
    float* att = G   + 524288;          // 2 * 256 * 256  = 131,072
    float* Y   = att + 131072;          // 8,388,608
    // total = 36,310,016 floats = 145.3 MB of ws

    dim3 T(256);

    // Projections Q, K, V for all 8 (s,b), batched via grid.z
    gemm_k<GM_PROJ><<<dim3(64, 1, 8), T, 0, stream>>>(Wq, nullptr, Q, bq, nullptr, nullptr, nullptr, xs,
                                                      32, 256, 256, HW, HW, 0, 0, 32 * HW);
    gemm_k<GM_PROJ><<<dim3(64, 1, 8), T, 0, stream>>>(Wk, nullptr, Km, bk, nullptr, nullptr, nullptr, xs,
                                                      32, 256, 256, HW, HW, 0, 0, 32 * HW);
    gemm_k<GM_PROJ><<<dim3(64, 4, 8), T, 0, stream>>>(Wv, nullptr, V, bv, nullptr, nullptr, nullptr, xs,
                                                      256, 256, 256, HW, HW, 0, 0, 256 * HW);

    // CAM: Gram matrices + softmax-sum over streams
    gemm_k<GM_GRAM><<<dim3(4, 4, 8), T, 0, stream>>>(nullptr, nullptr, G, nullptr, nullptr, nullptr, nullptr, xs,
                                                     256, HW, HW, HW, 256, 0, 0, 65536);
    cam_softmax_k<<<dim3(256, 2), T, 0, stream>>>(G, att);

    // PAM attention per (s,b): energy -> row stats -> PV (softmax fused in B-load)
    for (int sb = 0; sb < 8; ++sb) {
        const float* Qs = Q  + (size_t)sb * 32 * HW;
        const float* Ks = Km + (size_t)sb * 32 * HW;
        const float* Vs = V  + (size_t)sb * 256 * HW;
        float*       Ys = Y  + (size_t)sb * 256 * HW;
        gemm_k<GM_E><<<dim3(64, 64, 1), T, 0, stream>>>(Qs, Ks, E, nullptr, nullptr, nullptr, nullptr, xs,
                                                        HW, 32, HW, HW, HW, 0, 0, 0);
        rowstats_k<<<dim3(4096), T, 0, stream>>>(E, rmx, rsi);
        gemm_k<GM_PV><<<dim3(64, 4, 1), T, 0, stream>>>(Vs, E, Ys, nullptr, rmx, rsi, gp, xs,
                                                        256, HW, HW, HW, HW, 0, 0, 0);
    }

    // CAM apply: Y += gamma_cam * attsum[b] @ X + 5 * X
    gemm_k<GM_CAM><<<dim3(64, 4, 8), T, 0, stream>>>(att, nullptr, Y, nullptr, nullptr, nullptr, gc, xs,
                                                     256, 256, 256, HW, HW, 65536, 0, 256 * HW);

    // 3x3 conv as implicit GEMM: d_out = Wd (*) Y + bd
    gemm_k<GM_CONV><<<dim3(64, 4, 8), T, 0, stream>>>(Wd, Y, (float*)d_out, bd, nullptr, nullptr, nullptr, xs,
                                                      256, 2304, 2304, HW, HW, 0, 256 * HW, 256 * HW);
}

// Round 3
// 1694.063 us; speedup vs baseline: 1.9625x; 1.9625x over previous
//
#include <hip/hip_runtime.h>

// FeatureEnhance: 4-stream PAM + CAM + shared 3x3 conv.
// S=4, B=2, C=256, CQ=32, H=W=64, N=HW=4096.
// Round 2: PV + CONV moved to bf16 MFMA (16x16x32, m97-style 128^2 tile,
// global_load_lds staging, packed-K8 B operands). E -> bf16. Rest f32 SIMT.

#define HW 4096

typedef unsigned short u16;
typedef __attribute__((ext_vector_type(4))) float f32x4;
typedef __attribute__((ext_vector_type(8))) short bf16x8;
typedef __attribute__((ext_vector_type(8))) unsigned short u16x8;
typedef __attribute__((ext_vector_type(4))) unsigned short u16x4;

__device__ __forceinline__ float bf2f(u16 u) { return __uint_as_float(((unsigned)u) << 16); }
__device__ __forceinline__ u16 f2bf(float f) {
    unsigned x = __float_as_uint(f);
    return (u16)((x + 0x7fffu + ((x >> 16) & 1u)) >> 16);
}

__device__ __forceinline__ void gload16(const void* g, void* l) {
    __builtin_amdgcn_global_load_lds((const __attribute__((address_space(1))) void*)g,
                                     (__attribute__((address_space(3))) void*)l, 16, 0, 0);
}

struct XPtrs { const float* p[4]; };

enum { GM_PROJ = 0, GM_PROJH = 1, GM_E = 2, GM_GRAM = 3, GM_CAM = 4 };

// ---------------- f32 SIMT GEMM (small/remaining ops) ----------------
//   GM_PROJ : A=W (NN), B=X (xs), +bias, f32 out          (Q, K proj)
//   GM_PROJH: same, bf16 out                              (V proj)
//   GM_E    : A=Q^T, B=K (NN); bf16 out (energy)
//   GM_GRAM : A=X, B=X^T (NT); f32 out
//   GM_CAM  : A=attsum[b], B=X; epilogue Y += g*acc + 5*X
template<int MODE>
__global__ __launch_bounds__(256)
void gemm_k(const float* __restrict__ A, const float* __restrict__ Bp,
            void* __restrict__ Cp, const float* __restrict__ bias,
            const float* __restrict__ gscale, XPtrs xs,
            int M, int K, int lda, int ldb, int ldc,
            long aBatch, long bBatch, long cBatch)
{
    const int bx = blockIdx.x, by = blockIdx.y, bz = blockIdx.z;
    const int n0 = bx * 64, m0 = by * 64;
    const int t  = threadIdx.x;
    const int tm = t >> 4, tn = t & 15;

    const float* xb = nullptr;
    if constexpr (MODE == GM_PROJ || MODE == GM_PROJH || MODE == GM_GRAM || MODE == GM_CAM)
        xb = xs.p[bz >> 1] + (size_t)(bz & 1) * (256 * HW);

    const float* Ab;
    if constexpr (MODE == GM_GRAM)      Ab = xb;
    else if constexpr (MODE == GM_CAM)  Ab = A + (size_t)(bz & 1) * aBatch;
    else                                Ab = A + (size_t)bz * aBatch;

    const float* Bb;
    if constexpr (MODE == GM_PROJ || MODE == GM_PROJH || MODE == GM_GRAM || MODE == GM_CAM) Bb = xb;
    else Bb = Bp + (size_t)bz * bBatch;

    __shared__ float As[16][68];
    __shared__ float Bs[16][68];

    float acc[4][4] = {};

    for (int kb = 0; kb < K; kb += 16) {
        if constexpr (MODE == GM_E) {
            const int k = t >> 4, i0 = (t & 15) * 4;
            float4 v = *(const float4*)(Ab + (size_t)(kb + k) * lda + (m0 + i0));
            *(float4*)&As[k][i0] = v;
        } else {
            const int m = t >> 2, k0 = (t & 3) * 4;
            float4 v = make_float4(0.f, 0.f, 0.f, 0.f);
            if (m0 + m < M)
                v = *(const float4*)(Ab + (size_t)(m0 + m) * lda + (kb + k0));
            As[k0 + 0][m] = v.x;
            As[k0 + 1][m] = v.y;
            As[k0 + 2][m] = v.z;
            As[k0 + 3][m] = v.w;
        }
        if constexpr (MODE == GM_GRAM) {
            const int n = t >> 2, k0 = (t & 3) * 4;
            float4 v = *(const float4*)(Bb + (size_t)(n0 + n) * ldb + (kb + k0));
            Bs[k0 + 0][n] = v.x;
            Bs[k0 + 1][n] = v.y;
            Bs[k0 + 2][n] = v.z;
            Bs[k0 + 3][n] = v.w;
        } else {
            const int k = t >> 4, c0 = (t & 15) * 4;
            float4 v = *(const float4*)(Bb + (size_t)(kb + k) * ldb + (n0 + c0));
            *(float4*)&Bs[k][c0] = v;
        }
        __syncthreads();

        #pragma unroll
        for (int k = 0; k < 16; ++k) {
            const float4 a = *(const float4*)&As[k][tm * 4];
            const float4 b = *(const float4*)&Bs[k][tn * 4];
            acc[0][0] += a.x * b.x; acc[0][1] += a.x * b.y; acc[0][2] += a.x * b.z; acc[0][3] += a.x * b.w;
            acc[1][0] += a.y * b.x; acc[1][1] += a.y * b.y; acc[1][2] += a.y * b.z; acc[1][3] += a.y * b.w;
            acc[2][0] += a.z * b.x; acc[2][1] += a.z * b.y; acc[2][2] += a.z * b.z; acc[2][3] += a.z * b.w;
            acc[3][0] += a.w * b.x; acc[3][1] += a.w * b.y; acc[3][2] += a.w * b.z; acc[3][3] += a.w * b.w;
        }
        __syncthreads();
    }

    float g = 0.f;
    if constexpr (MODE == GM_CAM) g = gscale[0];

    #pragma unroll
    for (int i = 0; i < 4; ++i) {
        const int m = m0 + tm * 4 + i;
        if (m >= M) continue;
        float4 r = make_float4(acc[i][0], acc[i][1], acc[i][2], acc[i][3]);
        if constexpr (MODE == GM_PROJ || MODE == GM_PROJH) {
            const float bi = bias[m];
            r.x += bi; r.y += bi; r.z += bi; r.w += bi;
        }
        const size_t off = (size_t)m * ldc + (n0 + tn * 4);
        if constexpr (MODE == GM_PROJH || MODE == GM_E) {
            u16* Ch = (u16*)Cp + (size_t)bz * cBatch;
            u16 o[4] = { f2bf(r.x), f2bf(r.y), f2bf(r.z), f2bf(r.w) };
            *(u16x4*)&Ch[off] = *(u16x4*)o;
        } else {
            float* Cf = (float*)Cp + (size_t)bz * cBatch;
            if constexpr (MODE == GM_CAM) {
                const float4 yv = *(const float4*)&Cf[off];
                const float4 xv = *(const float4*)(xb + (size_t)m * HW + (n0 + tn * 4));
                r.x = yv.x + g * r.x + 5.f * xv.x;
                r.y = yv.y + g * r.y + 5.f * xv.y;
                r.z = yv.z + g * r.z + 5.f * xv.z;
                r.w = yv.w + g * r.w + 5.f * xv.w;
            }
            *(float4*)&Cf[off] = r;
        }
    }
}

// ---------------- bf16 MFMA GEMM: C[m,n] = sum_k A[m,k]*Bpack[k,n] ----------------
// A row-major bf16 (lda elems). Bpack: [k>>3][n(4096)][k&7] bf16.
// BM=BN=128, BK=32, 256 threads = 4 waves, each wave owns a 64x64 quadrant.
enum { MM_PV = 0, MM_CONV = 1 };

template<int MODE>
__global__ __launch_bounds__(256)
void mfma_nn_k(const u16* __restrict__ A, const u16* __restrict__ Bp,
               float* __restrict__ C, const float* __restrict__ bias,
               const float* __restrict__ gscale,
               int K, int lda, long aBatch, long bBatch, long cBatch)
{
    const int n0 = blockIdx.x * 128, m0 = blockIdx.y * 128, z = blockIdx.z;
    const u16* Ab = A + (size_t)z * aBatch + (size_t)m0 * lda;
    const u16* Bb = Bp + (size_t)z * bBatch + (size_t)n0 * 8;
    float* Cb = C + (size_t)z * cBatch;

    __shared__ u16 As[4096];   // [kh][m][kl] : kh*1024 + m*8 + kl
    __shared__ u16 Bs[4096];   // [kh][n][kl]

    const int t = threadIdx.x, lane = t & 63, w = t >> 6;
    const int mw = (w >> 1) * 64, nw = (w & 1) * 64;
    const int l15 = lane & 15, l4 = lane >> 4;

    f32x4 acc[4][4] = {};

    const u16* gaw = Ab + (size_t)lane * lda + w * 8;
    const u16* gbw = Bb + (size_t)w * (HW * 8) + (size_t)lane * 8;

    for (int kb = 0; kb < K; kb += 32) {
        // stage A tile: wave w covers kh=w, m halves 0/1
        gload16(gaw + kb,                    &As[w * 1024]);
        gload16(gaw + kb + (size_t)64 * lda, &As[w * 1024 + 512]);
        // stage B tile: wave w covers kh=w, n halves 0/1
        const u16* gb = gbw + (size_t)(kb >> 3) * (HW * 8);
        gload16(gb,       &Bs[w * 1024]);
        gload16(gb + 512, &Bs[w * 1024 + 512]);
        __syncthreads();

        bf16x8 af[4], bf[4];
        #pragma unroll
        for (int i = 0; i < 4; ++i) {
            af[i] = *(const bf16x8*)&As[l4 * 1024 + (mw + i * 16 + l15) * 8];
            bf[i] = *(const bf16x8*)&Bs[l4 * 1024 + (nw + i * 16 + l15) * 8];
        }
        #pragma unroll
        for (int mi = 0; mi < 4; ++mi)
            #pragma unroll
            for (int ni = 0; ni < 4; ++ni)
                acc[mi][ni] = __builtin_amdgcn_mfma_f32_16x16x32_bf16(af[mi], bf[ni], acc[mi][ni], 0, 0, 0);
        __syncthreads();
    }

    float g = 1.f;
    if constexpr (MODE == MM_PV) g = gscale[0];

    #pragma unroll
    for (int mi = 0; mi < 4; ++mi) {
        #pragma unroll
        for (int ni = 0; ni < 4; ++ni) {
            #pragma unroll
            for (int r = 0; r < 4; ++r) {
                const int row = m0 + mw + mi * 16 + l4 * 4 + r;
                const int col = n0 + nw + ni * 16 + l15;
                float v = acc[mi][ni][r];
                if constexpr (MODE == MM_PV) v *= g;
                else                         v += bias[row];
                Cb[(size_t)row * HW + col] = v;
            }
        }
    }
}

// -------- per-row max and 1/sum(exp) over bf16 E rows --------
__global__ __launch_bounds__(256)
void rowstats_k(const u16* __restrict__ E, float* __restrict__ rmax,
                float* __restrict__ rsinv)
{
    __shared__ float red[4];
    __shared__ float bmax;
    const int t = threadIdx.x;
    const u16* row = E + (size_t)blockIdx.x * HW;

    float m = -3.4e38f;
    for (int i = t * 8; i < HW; i += 2048) {
        const u16x8 v = *(const u16x8*)&row[i];
        #pragma unroll
        for (int j = 0; j < 8; ++j) m = fmaxf(m, bf2f(v[j]));
    }
    for (int o = 32; o; o >>= 1) m = fmaxf(m, __shfl_down(m, o));
    if ((t & 63) == 0) red[t >> 6] = m;
    __syncthreads();
    if (t == 0) bmax = fmaxf(fmaxf(red[0], red[1]), fmaxf(red[2], red[3]));
    __syncthreads();
    m = bmax;

    float s = 0.f;
    for (int i = t * 8; i < HW; i += 2048) {
        const u16x8 v = *(const u16x8*)&row[i];
        #pragma unroll
        for (int j = 0; j < 8; ++j) s += __expf(bf2f(v[j]) - m);
    }
    for (int o = 32; o; o >>= 1) s += __shfl_down(s, o);
    if ((t & 63) == 0) red[t >> 6] = s;
    __syncthreads();
    if (t == 0) {
        rmax[blockIdx.x]  = m;
        rsinv[blockIdx.x] = 1.0f / (red[0] + red[1] + red[2] + red[3]);
    }
}

// -------- exp-transpose: Ppack[m>>3][j][m&7] = bf16(exp(E[j][m]-rmax[j])*rsinv[j]) --------
__global__ __launch_bounds__(256)
void expT_k(const u16* __restrict__ Eh, const float* __restrict__ rmax,
            const float* __restrict__ rsinv, u16* __restrict__ Pp)
{
    __shared__ u16 tile[64 * 64];  // [j][slot][8], slot = mg ^ (j&7)
    const int m0 = blockIdx.x * 64, j0 = blockIdx.y * 64;
    const int t = threadIdx.x;
    const int tm8 = t & 7, tj = t >> 3;

    #pragma unroll
    for (int p = 0; p < 2; ++p) {
        const int j = tj + p * 32;
        const u16x8 ev = *(const u16x8*)&Eh[(size_t)(j0 + j) * HW + m0 + tm8 * 8];
        const float mx = rmax[j0 + j], ri = rsinv[j0 + j];
        u16 pv[8];
        #pragma unroll
        for (int i = 0; i < 8; ++i) pv[i] = f2bf(__expf(bf2f(ev[i]) - mx) * ri);
        const int slot = tm8 ^ (j & 7);
        *(u16x8*)&tile[j * 64 + slot * 8] = *(u16x8*)pv;
    }
    __syncthreads();

    const int mg = t >> 5, jj = t & 31;
    #pragma unroll
    for (int p = 0; p < 2; ++p) {
        const int j = jj + p * 32;
        const int slot = mg ^ (j & 7);
        const u16x8 v = *(const u16x8*)&tile[j * 64 + slot * 8];
        *(u16x8*)&Pp[(((size_t)(m0 >> 3) + mg) * HW + (j0 + j)) * 8] = v;
    }
}

// -------- im2col (bf16, packed-K8): col[kg][n][kl] = Y[ic][ih][iw] --------
__global__ __launch_bounds__(256)
void im2col_k(const float* __restrict__ Y, u16* __restrict__ col, int sb0)
{
    const int n = blockIdx.x * 256 + threadIdx.x;
    const int kg = blockIdx.y;
    const int sbl = blockIdx.z;
    const float* Yb = Y + (size_t)(sb0 + sbl) * (256 * HW);
    const int h = n >> 6, wc = n & 63;
    u16 out[8];
    #pragma unroll
    for (int kl = 0; kl < 8; ++kl) {
        const int k = kg * 8 + kl;
        const int ic = k / 9, r = k - ic * 9;
        const int ih = h + r / 3 - 1, iw = wc + (r % 3) - 1;
        float v = 0.f;
        if (ih >= 0 && ih < 64 && iw >= 0 && iw < 64)
            v = Yb[(size_t)ic * HW + (ih << 6) + iw];
        out[kl] = f2bf(v);
    }
    *(u16x8*)&col[(((size_t)sbl * 288 + kg) * HW + n) * 8] = *(u16x8*)out;
}

// -------- Wd f32 -> bf16 --------
__global__ __launch_bounds__(256)
void cvt_wd_k(const float* __restrict__ Wd, u16* __restrict__ Wh)
{
    const size_t i = ((size_t)blockIdx.x * 256 + threadIdx.x) * 4;
    const float4 v = *(const float4*)&Wd[i];
    u16 o[4] = { f2bf(v.x), f2bf(v.y), f2bf(v.z), f2bf(v.w) };
    *(u16x4*)&Wh[i] = *(u16x4*)o;
}

// -------- CAM softmax (unchanged) --------
__global__ __launch_bounds__(256)
void cam_softmax_k(const float* __restrict__ G, float* __restrict__ attsum)
{
    __shared__ float rmn[4], rsm[4];
    const int c = blockIdx.x, b = blockIdx.y;
    const int d = threadIdx.x;
    float acc = 0.f;
    for (int s = 0; s < 4; ++s) {
        const float* row = G + (((size_t)(s * 2 + b)) * 256 + c) * 256;
        const float e = row[d];
        float mn = e;
        for (int o = 32; o; o >>= 1) mn = fminf(mn, __shfl_down(mn, o));
        if ((d & 63) == 0) rmn[d >> 6] = mn;
        __syncthreads();
        mn = fminf(fminf(rmn[0], rmn[1]), fminf(rmn[2], rmn[3]));
        const float ex = __expf(mn - e);
        float sm = ex;
        for (int o = 32; o; o >>= 1) sm += __shfl_down(sm, o);
        if ((d & 63) == 0) rsm[d >> 6] = sm;
        __syncthreads();
        sm = rsm[0] + rsm[1] + rsm[2] + rsm[3];
        acc += ex * (1.0f / sm);
        __syncthreads();
    }
    attsum[((size_t)b * 256 + c) * 256 + d] = acc;
}

extern "C" void kernel_launch(void* const* d_in, const int* in_sizes, int n_in,
                              void* d_out, int out_size, void* d_ws, size_t ws_size,
                              hipStream_t stream)
{
    XPtrs xs;
    xs.p[0] = (const float*)d_in[0];
    xs.p[1] = (const float*)d_in[1];
    xs.p[2] = (const float*)d_in[2];
    xs.p[3] = (const float*)d_in[3];
    const float* Wq = (const float*)d_in[4];
    const float* bq = (const float*)d_in[5];
    const float* Wk = (const float*)d_in[6];
    const float* bk = (const float*)d_in[7];
    const float* Wv = (const float*)d_in[8];
    const float* bv = (const float*)d_in[9];
    const float* gp = (const float*)d_in[10];
    const float* gc = (const float*)d_in[11];
    const float* Wd = (const float*)d_in[12];
    const float* bd = (const float*)d_in[13];

    char* base = (char*)d_ws;
    size_t off = 0;
    auto alloc = [&](size_t bytes) -> char* {
        char* p = base + off;
        off = (off + bytes + 255) & ~(size_t)255;
        return p;
    };

    float* G    = (float*)alloc((size_t)8 * 256 * 256 * 4);     // 2 MB
    float* att  = (float*)alloc((size_t)2 * 256 * 256 * 4);     // 0.5 MB
    float* rmx  = (float*)alloc(4096 * 4);
    float* rsi  = (float*)alloc(4096 * 4);
    float* Y    = (float*)alloc((size_t)8 * 256 * HW * 4);      // 32 MB
    u16*   Vh   = (u16*)  alloc((size_t)8 * 256 * HW * 2);      // 16 MB
    u16*   Wdh  = (u16*)  alloc((size_t)256 * 2304 * 2);        // 1.1 MB
    const size_t fixedEnd = off;
    float* Qf   = (float*)alloc((size_t)8 * 32 * HW * 4);       // 4 MB
    float* Kf   = (float*)alloc((size_t)8 * 32 * HW * 4);       // 4 MB
    u16*   Eh   = (u16*)  alloc((size_t)HW * HW * 2);           // 32 MB
    const size_t ppOff = off;
    u16*   Pp   = (u16*)(base + ppOff);
    const size_t ppPer = (size_t)HW * HW * 2;                   // 32 MB / sb
    const int ppN = (ws_size >= ppOff + 8 * ppPer) ? 8 : 1;     // batched PV if ws allows

    // conv colpack overlays the (dead-by-then) PAM region
    const size_t colPer = (size_t)288 * HW * 8 * 2;             // 18.9 MB / sb
    u16* colp = (u16*)(base + fixedEnd);
    long nchunkL = (long)((ws_size - fixedEnd) / colPer);
    int nchunk = (int)(nchunkL > 8 ? 8 : (nchunkL < 1 ? 1 : nchunkL));

    dim3 T(256);

    // Projections: Q, K f32; V bf16
    gemm_k<GM_PROJ><<<dim3(64, 1, 8), T, 0, stream>>>(Wq, nullptr, Qf, bq, nullptr, xs,
                                                      32, 256, 256, HW, HW, 0, 0, 32 * HW);
    gemm_k<GM_PROJ><<<dim3(64, 1, 8), T, 0, stream>>>(Wk, nullptr, Kf, bk, nullptr, xs,
                                                      32, 256, 256, HW, HW, 0, 0, 32 * HW);
    gemm_k<GM_PROJH><<<dim3(64, 4, 8), T, 0, stream>>>(Wv, nullptr, Vh, bv, nullptr, xs,
                                                       256, 256, 256, HW, HW, 0, 0, 256 * HW);
    cvt_wd_k<<<dim3(576), T, 0, stream>>>(Wd, Wdh);

    // CAM: Gram + softmax-sum
    gemm_k<GM_GRAM><<<dim3(4, 4, 8), T, 0, stream>>>(nullptr, nullptr, G, nullptr, nullptr, xs,
                                                     256, HW, HW, HW, 256, 0, 0, 65536);
    cam_softmax_k<<<dim3(256, 2), T, 0, stream>>>(G, att);

    // PAM: per (s,b) energy -> stats -> packed softmax P; PV via MFMA
    for (int sb = 0; sb < 8; ++sb) {
        const float* Qs = Qf + (size_t)sb * 32 * HW;
        const float* Ks = Kf + (size_t)sb * 32 * HW;
        u16* Ppsb = Pp + (ppN == 8 ? (size_t)sb * (ppPer / 2) : 0);
        gemm_k<GM_E><<<dim3(64, 64, 1), T, 0, stream>>>(Qs, Ks, Eh, nullptr, nullptr, xs,
                                                        HW, 32, HW, HW, HW, 0, 0, 0);
        rowstats_k<<<dim3(4096), T, 0, stream>>>(Eh, rmx, rsi);
        expT_k<<<dim3(64, 64), T, 0, stream>>>(Eh, rmx, rsi, Ppsb);
        if (ppN == 1) {
            mfma_nn_k<MM_PV><<<dim3(32, 2, 1), T, 0, stream>>>(
                Vh + (size_t)sb * 256 * HW, Pp, Y + (size_t)sb * 256 * HW,
                nullptr, gp, HW, HW, 0, 0, 0);
        }
    }
    if (ppN == 8) {
        mfma_nn_k<MM_PV><<<dim3(32, 2, 8), T, 0, stream>>>(
            Vh, Pp, Y, nullptr, gp, HW, HW,
            (long)256 * HW, (long)HW * HW, (long)256 * HW);
    }

    // CAM apply: Y += gamma_cam * attsum[b] @ X + 5 * X
    gemm_k<GM_CAM><<<dim3(64, 4, 8), T, 0, stream>>>(att, nullptr, Y, nullptr, gc, xs,
                                                     256, 256, 256, HW, HW, 65536, 0, 256 * HW);

    // 3x3 conv: im2col (bf16 packed) + MFMA GEMM, chunked by ws capacity
    for (int c0 = 0; c0 < 8; c0 += nchunk) {
        const int cs = (8 - c0 < nchunk) ? (8 - c0) : nchunk;
        im2col_k<<<dim3(16, 288, cs), T, 0, stream>>>(Y, colp, c0);
        mfma_nn_k<MM_CONV><<<dim3(32, 2, cs), T, 0, stream>>>(
            Wdh, colp, (float*)d_out + (size_t)c0 * 256 * HW, bd, nullptr,
            2304, 2304, 0, (long)288 * HW * 8, (long)256 * HW);
    }
}

// Round 4
// 640.293 us; speedup vs baseline: 5.1923x; 2.6458x over previous
//
#include <hip/hip_runtime.h>

// FeatureEnhance: 4-stream PAM + CAM + shared 3x3 conv.
// S=4, B=2, C=256, CQ=32, H=W=64, N=HW=4096.
// Round 4: PAM chain fused into flash-attention MFMA kernel (no E/P
// materialization); split-K GRAM; conv unchanged (im2col + MFMA).

#define HW 4096

typedef unsigned short u16;
typedef __attribute__((ext_vector_type(4))) float f32x4;
typedef __attribute__((ext_vector_type(8))) short bf16x8;
typedef __attribute__((ext_vector_type(8))) unsigned short u16x8;
typedef __attribute__((ext_vector_type(4))) unsigned short u16x4;

__device__ __forceinline__ float bf2f(u16 u) { return __uint_as_float(((unsigned)u) << 16); }
__device__ __forceinline__ u16 f2bf(float f) {
    unsigned x = __float_as_uint(f);
    return (u16)((x + 0x7fffu + ((x >> 16) & 1u)) >> 16);
}

__device__ __forceinline__ void gload16(const void* g, void* l) {
    __builtin_amdgcn_global_load_lds((const __attribute__((address_space(1))) void*)g,
                                     (__attribute__((address_space(3))) void*)l, 16, 0, 0);
}

struct XPtrs { const float* p[4]; };

enum { GM_PROJ = 0, GM_PROJH = 1, GM_GRAM = 2, GM_CAM = 3 };

// ---------------- f32 SIMT GEMM (proj / gram / cam) ----------------
//   GM_PROJ : A=W (NN), B=X (xs), +bias, f32 out          (Q, K proj)
//   GM_PROJH: same, bf16 out                              (V proj)
//   GM_GRAM : A=X, B=X^T (NT), SPLIT-K: bz = sp*8+sb, K=512 slice -> Gp
//   GM_CAM  : A=attsum[b], B=X; epilogue Y += g*acc + 5*X
template<int MODE>
__global__ __launch_bounds__(256)
void gemm_k(const float* __restrict__ A, const float* __restrict__ Bp,
            void* __restrict__ Cp, const float* __restrict__ bias,
            const float* __restrict__ gscale, XPtrs xs,
            int M, int K, int lda, int ldb, int ldc,
            long aBatch, long bBatch, long cBatch)
{
    const int bx = blockIdx.x, by = blockIdx.y, bz = blockIdx.z;
    const int n0 = bx * 64, m0 = by * 64;
    const int t  = threadIdx.x;
    const int tm = t >> 4, tn = t & 15;

    int sbi = bz;
    if constexpr (MODE == GM_GRAM) sbi = bz & 7;

    const float* xb = xs.p[sbi >> 1] + (size_t)(sbi & 1) * (256 * HW);

    const float* Ab;
    if constexpr (MODE == GM_GRAM)      Ab = xb + (bz >> 3) * 512;
    else if constexpr (MODE == GM_CAM)  Ab = A + (size_t)(bz & 1) * aBatch;
    else                                Ab = A + (size_t)bz * aBatch;

    const float* Bb;
    if constexpr (MODE == GM_GRAM)      Bb = xb + (bz >> 3) * 512;
    else                                Bb = xb;

    __shared__ float As[16][68];
    __shared__ float Bs[16][68];

    float acc[4][4] = {};

    for (int kb = 0; kb < K; kb += 16) {
        {
            const int m = t >> 2, k0 = (t & 3) * 4;
            float4 v = make_float4(0.f, 0.f, 0.f, 0.f);
            if (m0 + m < M)
                v = *(const float4*)(Ab + (size_t)(m0 + m) * lda + (kb + k0));
            As[k0 + 0][m] = v.x;
            As[k0 + 1][m] = v.y;
            As[k0 + 2][m] = v.z;
            As[k0 + 3][m] = v.w;
        }
        if constexpr (MODE == GM_GRAM) {
            const int n = t >> 2, k0 = (t & 3) * 4;
            float4 v = *(const float4*)(Bb + (size_t)(n0 + n) * ldb + (kb + k0));
            Bs[k0 + 0][n] = v.x;
            Bs[k0 + 1][n] = v.y;
            Bs[k0 + 2][n] = v.z;
            Bs[k0 + 3][n] = v.w;
        } else {
            const int k = t >> 4, c0 = (t & 15) * 4;
            float4 v = *(const float4*)(Bb + (size_t)(kb + k) * ldb + (n0 + c0));
            *(float4*)&Bs[k][c0] = v;
        }
        __syncthreads();

        #pragma unroll
        for (int k = 0; k < 16; ++k) {
            const float4 a = *(const float4*)&As[k][tm * 4];
            const float4 b = *(const float4*)&Bs[k][tn * 4];
            acc[0][0] += a.x * b.x; acc[0][1] += a.x * b.y; acc[0][2] += a.x * b.z; acc[0][3] += a.x * b.w;
            acc[1][0] += a.y * b.x; acc[1][1] += a.y * b.y; acc[1][2] += a.y * b.z; acc[1][3] += a.y * b.w;
            acc[2][0] += a.z * b.x; acc[2][1] += a.z * b.y; acc[2][2] += a.z * b.z; acc[2][3] += a.z * b.w;
            acc[3][0] += a.w * b.x; acc[3][1] += a.w * b.y; acc[3][2] += a.w * b.z; acc[3][3] += a.w * b.w;
        }
        __syncthreads();
    }

    float g = 0.f;
    if constexpr (MODE == GM_CAM) g = gscale[0];

    #pragma unroll
    for (int i = 0; i < 4; ++i) {
        const int m = m0 + tm * 4 + i;
        if (m >= M) continue;
        float4 r = make_float4(acc[i][0], acc[i][1], acc[i][2], acc[i][3]);
        if constexpr (MODE == GM_PROJ || MODE == GM_PROJH) {
            const float bi = bias[m];
            r.x += bi; r.y += bi; r.z += bi; r.w += bi;
        }
        const size_t off = (size_t)m * ldc + (n0 + tn * 4);
        if constexpr (MODE == GM_PROJH) {
            u16* Ch = (u16*)Cp + (size_t)bz * cBatch;
            u16 o[4] = { f2bf(r.x), f2bf(r.y), f2bf(r.z), f2bf(r.w) };
            *(u16x4*)&Ch[off] = *(u16x4*)o;
        } else {
            float* Cf = (float*)Cp + (size_t)bz * cBatch;
            if constexpr (MODE == GM_CAM) {
                const float4 yv = *(const float4*)&Cf[off];
                const float4 xv = *(const float4*)(xb + (size_t)m * HW + (n0 + tn * 4));
                r.x = yv.x + g * r.x + 5.f * xv.x;
                r.y = yv.y + g * r.y + 5.f * xv.y;
                r.z = yv.z + g * r.z + 5.f * xv.z;
                r.w = yv.w + g * r.w + 5.f * xv.w;
            }
            *(float4*)&Cf[off] = r;
        }
    }
}

// -------- Gp reduce: G[i] = sum_sp Gp[sp][i] --------
__global__ __launch_bounds__(256)
void greduce_k(const float* __restrict__ Gp, float* __restrict__ G)
{
    const size_t i = (size_t)blockIdx.x * 256 + threadIdx.x;  // [0, 8*65536)
    float s = 0.f;
    #pragma unroll
    for (int sp = 0; sp < 8; ++sp) s += Gp[(size_t)sp * 524288 + i];
    G[i] = s;
}

// -------- CAM softmax: attsum[b][c][d] = sum_s exp(min-e)/sum --------
__global__ __launch_bounds__(256)
void cam_softmax_k(const float* __restrict__ G, float* __restrict__ attsum)
{
    __shared__ float rmn[4], rsm[4];
    const int c = blockIdx.x, b = blockIdx.y;
    const int d = threadIdx.x;
    float acc = 0.f;
    for (int s = 0; s < 4; ++s) {
        const float* row = G + (((size_t)(s * 2 + b)) * 256 + c) * 256;
        const float e = row[d];
        float mn = e;
        for (int o = 32; o; o >>= 1) mn = fminf(mn, __shfl_down(mn, o));
        if ((d & 63) == 0) rmn[d >> 6] = mn;
        __syncthreads();
        mn = fminf(fminf(rmn[0], rmn[1]), fminf(rmn[2], rmn[3]));
        const float ex = __expf(mn - e);
        float sm = ex;
        for (int o = 32; o; o >>= 1) sm += __shfl_down(sm, o);
        if ((d & 63) == 0) rsm[d >> 6] = sm;
        __syncthreads();
        sm = rsm[0] + rsm[1] + rsm[2] + rsm[3];
        acc += ex * (1.0f / sm);
        __syncthreads();
    }
    attsum[((size_t)b * 256 + c) * 256 + d] = acc;
}

// -------- transpose+convert: src [sb][32][4096] f32 -> dst [sb][4096][32] bf16 --------
__global__ __launch_bounds__(256)
void tqk_k(const float* __restrict__ src, u16* __restrict__ dst)
{
    __shared__ float tile[64][33];
    const int sb = blockIdx.y;
    const int n0 = blockIdx.x * 64;
    const float* s = src + (size_t)sb * (32 * HW);
    u16* d = dst + (size_t)sb * (HW * 32);
    const int t = threadIdx.x;
    {
        const int c = t >> 3, np = (t & 7) * 8;
        const float4* s4 = (const float4*)&s[(size_t)c * HW + n0 + np];
        const float4 a = s4[0], b = s4[1];
        tile[np + 0][c] = a.x; tile[np + 1][c] = a.y; tile[np + 2][c] = a.z; tile[np + 3][c] = a.w;
        tile[np + 4][c] = b.x; tile[np + 5][c] = b.y; tile[np + 6][c] = b.z; tile[np + 7][c] = b.w;
    }
    __syncthreads();
    const int n = t >> 2, cp = (t & 3) * 8;
    u16 o[8];
    #pragma unroll
    for (int i = 0; i < 8; ++i) o[i] = f2bf(tile[n][cp + i]);
    *(u16x8*)&d[(size_t)(n0 + n) * 32 + cp] = *(u16x8*)o;
}

// ---------------- fused flash PAM: Yt[n][c] = gp * (softmax(Qt Kt^T) @ V^T)[n][c] ----------------
// Qt,Kt: [sb][4096][32] bf16. Vh: [sb][256][4096] bf16. Yt: [sb][4096][256] f32.
// 8 waves: qg = w&3 owns 32 q-rows, ch = w>>2 owns 128 of 256 V-channels.
// Waves w<4 compute S + online softmax, publish P (swizzled LDS) + scale; all waves do PV.
__global__ __launch_bounds__(512, 2)
void flash_k(const u16* __restrict__ Qt, const u16* __restrict__ Kt,
             const u16* __restrict__ Vh, float* __restrict__ Yt,
             const float* __restrict__ gscale)
{
    __shared__ u16 Vs[256 * 128];     // 64KB: [c][chunk^ (c&7)][8]
    __shared__ u16 Ps[4][32 * 128];   // 32KB: [qg][qrow][chunk ^ (qrow&7)][8]
    __shared__ float Sc[4][32];       // per-iter row rescale; final 1/l

    const int sb = blockIdx.y;
    const int t = threadIdx.x, w = t >> 6, lane = t & 63;
    const int l15 = lane & 15, l4 = lane >> 4;
    const int qg = w & 3, ch = w >> 2;
    const int q0 = blockIdx.x * 128 + qg * 32;
    const int c0 = ch * 128;

    const u16* Qb = Qt + (size_t)sb * (HW * 32);
    const u16* Kb = Kt + (size_t)sb * (HW * 32);
    const u16* Vb = Vh + (size_t)sb * ((size_t)256 * HW);
    float* Yb = Yt + (size_t)sb * ((size_t)HW * 256);

    bf16x8 aq[2];
    aq[0] = *(const bf16x8*)&Qb[(size_t)(q0 + l15) * 32 + l4 * 8];
    aq[1] = *(const bf16x8*)&Qb[(size_t)(q0 + 16 + l15) * 32 + l4 * 8];

    f32x4 acc[2][8] = {};
    float mrun[2][4], lrun[2][4];
    #pragma unroll
    for (int a = 0; a < 2; ++a)
        #pragma unroll
        for (int r = 0; r < 4; ++r) { mrun[a][r] = -3.0e38f; lrun[a][r] = 0.f; }

    const f32x4 zero4 = {0.f, 0.f, 0.f, 0.f};

    for (int it = 0; it < 32; ++it) {
        const int m0 = it * 128;

        // K fragments from global (L2-resident), only softmax waves need them
        bf16x8 bk[8];
        if (w < 4) {
            #pragma unroll
            for (int j = 0; j < 8; ++j)
                bk[j] = *(const bf16x8*)&Kb[(size_t)(m0 + j * 16 + l15) * 32 + l4 * 8];
        }

        // stage V tile [256][128] bf16 -> LDS, pre-swizzled source (T2/rule21)
        #pragma unroll
        for (int i = 0; i < 8; ++i) {
            const int chunk = i * 512 + t;
            const int c = chunk >> 4, kc = chunk & 15;
            const int mo = kc ^ (c & 7);
            gload16(Vb + (size_t)c * HW + m0 + mo * 8, &Vs[(size_t)(i * 512 + w * 64) * 8]);
        }

        if (w < 4) {
            // S = Q K^T  (f32 acc)
            f32x4 s[2][8];
            #pragma unroll
            for (int qt = 0; qt < 2; ++qt)
                #pragma unroll
                for (int j = 0; j < 8; ++j)
                    s[qt][j] = __builtin_amdgcn_mfma_f32_16x16x32_bf16(aq[qt], bk[j], zero4, 0, 0, 0);

            // online softmax; publish P + scale
            #pragma unroll
            for (int qt = 0; qt < 2; ++qt) {
                #pragma unroll
                for (int r = 0; r < 4; ++r) {
                    float tmax = s[qt][0][r];
                    #pragma unroll
                    for (int j = 1; j < 8; ++j) tmax = fmaxf(tmax, s[qt][j][r]);
                    tmax = fmaxf(tmax, __shfl_xor(tmax, 1));
                    tmax = fmaxf(tmax, __shfl_xor(tmax, 2));
                    tmax = fmaxf(tmax, __shfl_xor(tmax, 4));
                    tmax = fmaxf(tmax, __shfl_xor(tmax, 8));
                    const float mnew = fmaxf(mrun[qt][r], tmax);
                    const float scl = __expf(mrun[qt][r] - mnew);
                    mrun[qt][r] = mnew;

                    const int qrow = qt * 16 + l4 * 4 + r;
                    float tsum = 0.f;
                    #pragma unroll
                    for (int j = 0; j < 8; ++j) {
                        const float p = __expf(s[qt][j][r] - mnew);
                        tsum += p;
                        const int chk = (j * 2 + (l15 >> 3)) ^ (qrow & 7);
                        Ps[qg][qrow * 128 + chk * 8 + (l15 & 7)] = f2bf(p);
                    }
                    tsum += __shfl_xor(tsum, 1);
                    tsum += __shfl_xor(tsum, 2);
                    tsum += __shfl_xor(tsum, 4);
                    tsum += __shfl_xor(tsum, 8);
                    lrun[qt][r] = lrun[qt][r] * scl + tsum;

                    if (l15 == 0) Sc[qg][qrow] = scl;
                    #pragma unroll
                    for (int ct = 0; ct < 8; ++ct) acc[qt][ct][r] *= scl;
                }
            }
        }
        __syncthreads();   // V staged; P + Sc visible

        if (w >= 4) {
            #pragma unroll
            for (int qt = 0; qt < 2; ++qt)
                #pragma unroll
                for (int r = 0; r < 4; ++r) {
                    const float scl = Sc[qg][qt * 16 + l4 * 4 + r];
                    #pragma unroll
                    for (int ct = 0; ct < 8; ++ct) acc[qt][ct][r] *= scl;
                }
        }

        // PV
        #pragma unroll
        for (int ks = 0; ks < 4; ++ks) {
            bf16x8 ap[2];
            #pragma unroll
            for (int qt = 0; qt < 2; ++qt) {
                const int qr = qt * 16 + l15;
                ap[qt] = *(const bf16x8*)&Ps[qg][qr * 128 + (((ks * 4 + l4) ^ (qr & 7)) << 3)];
            }
            #pragma unroll
            for (int ct = 0; ct < 8; ++ct) {
                const int c = c0 + ct * 16 + l15;
                const bf16x8 bv = *(const bf16x8*)&Vs[(size_t)c * 128 + (((ks * 4 + l4) ^ (c & 7)) << 3)];
                acc[0][ct] = __builtin_amdgcn_mfma_f32_16x16x32_bf16(ap[0], bv, acc[0][ct], 0, 0, 0);
                acc[1][ct] = __builtin_amdgcn_mfma_f32_16x16x32_bf16(ap[1], bv, acc[1][ct], 0, 0, 0);
            }
        }
        __syncthreads();   // done reading Vs/Ps before next stage
    }

    // publish 1/l, normalize, write Yt (coalesced along c)
    if (w < 4 && l15 == 0) {
        #pragma unroll
        for (int qt = 0; qt < 2; ++qt)
            #pragma unroll
            for (int r = 0; r < 4; ++r)
                Sc[qg][qt * 16 + l4 * 4 + r] = 1.0f / lrun[qt][r];
    }
    __syncthreads();
    const float gp = gscale[0];
    #pragma unroll
    for (int qt = 0; qt < 2; ++qt) {
        #pragma unroll
        for (int r = 0; r < 4; ++r) {
            const float linv = Sc[qg][qt * 16 + l4 * 4 + r];
            const int row = q0 + qt * 16 + l4 * 4 + r;
            #pragma unroll
            for (int ct = 0; ct < 8; ++ct)
                Yb[(size_t)row * 256 + c0 + ct * 16 + l15] = gp * acc[qt][ct][r] * linv;
        }
    }
}

// -------- tiled transpose: Yt [sb][4096][256] f32 -> Y [sb][256][4096] f32 --------
__global__ __launch_bounds__(256)
void transT_k(const float* __restrict__ Yt, float* __restrict__ Y)
{
    __shared__ float tile[64][65];
    const int sb = blockIdx.z;
    const int n0 = blockIdx.x * 64, c0 = blockIdx.y * 64;
    const float* src = Yt + (size_t)sb * ((size_t)HW * 256);
    float* dst = Y + (size_t)sb * ((size_t)256 * HW);
    const int t = threadIdx.x;
    {
        const int n = t >> 2, p = t & 3;
        const float4* s4 = (const float4*)&src[(size_t)(n0 + n) * 256 + c0 + p * 16];
        #pragma unroll
        for (int i = 0; i < 4; ++i) {
            const float4 v = s4[i];
            tile[n][p * 16 + i * 4 + 0] = v.x;
            tile[n][p * 16 + i * 4 + 1] = v.y;
            tile[n][p * 16 + i * 4 + 2] = v.z;
            tile[n][p * 16 + i * 4 + 3] = v.w;
        }
    }
    __syncthreads();
    const int c = t >> 2, p = t & 3;
    #pragma unroll
    for (int i = 0; i < 4; ++i) {
        float4 v;
        v.x = tile[p * 16 + i * 4 + 0][c];
        v.y = tile[p * 16 + i * 4 + 1][c];
        v.z = tile[p * 16 + i * 4 + 2][c];
        v.w = tile[p * 16 + i * 4 + 3][c];
        *(float4*)&dst[(size_t)(c0 + c) * HW + n0 + p * 16 + i * 4] = v;
    }
}

// ---------------- bf16 MFMA GEMM (conv): C[m,n] = sum_k A[m,k]*Bpack[k,n] ----------------
__global__ __launch_bounds__(256)
void mfma_conv_k(const u16* __restrict__ A, const u16* __restrict__ Bp,
                 float* __restrict__ C, const float* __restrict__ bias,
                 int K, int lda, long bBatch, long cBatch)
{
    const int n0 = blockIdx.x * 128, m0 = blockIdx.y * 128, z = blockIdx.z;
    const u16* Ab = A + (size_t)m0 * lda;
    const u16* Bb = Bp + (size_t)z * bBatch + (size_t)n0 * 8;
    float* Cb = C + (size_t)z * cBatch;

    __shared__ u16 As[4096];   // [kh][m][kl]
    __shared__ u16 Bs[4096];   // [kh][n][kl]

    const int t = threadIdx.x, lane = t & 63, w = t >> 6;
    const int mw = (w >> 1) * 64, nw = (w & 1) * 64;
    const int l15 = lane & 15, l4 = lane >> 4;

    f32x4 acc[4][4] = {};

    const u16* gaw = Ab + (size_t)lane * lda + w * 8;
    const u16* gbw = Bb + (size_t)w * (HW * 8) + (size_t)lane * 8;

    for (int kb = 0; kb < K; kb += 32) {
        gload16(gaw + kb,                    &As[w * 1024]);
        gload16(gaw + kb + (size_t)64 * lda, &As[w * 1024 + 512]);
        const u16* gb = gbw + (size_t)(kb >> 3) * (HW * 8);
        gload16(gb,       &Bs[w * 1024]);
        gload16(gb + 512, &Bs[w * 1024 + 512]);
        __syncthreads();

        bf16x8 af[4], bf[4];
        #pragma unroll
        for (int i = 0; i < 4; ++i) {
            af[i] = *(const bf16x8*)&As[l4 * 1024 + (mw + i * 16 + l15) * 8];
            bf[i] = *(const bf16x8*)&Bs[l4 * 1024 + (nw + i * 16 + l15) * 8];
        }
        #pragma unroll
        for (int mi = 0; mi < 4; ++mi)
            #pragma unroll
            for (int ni = 0; ni < 4; ++ni)
                acc[mi][ni] = __builtin_amdgcn_mfma_f32_16x16x32_bf16(af[mi], bf[ni], acc[mi][ni], 0, 0, 0);
        __syncthreads();
    }

    #pragma unroll
    for (int mi = 0; mi < 4; ++mi)
        #pragma unroll
        for (int ni = 0; ni < 4; ++ni)
            #pragma unroll
            for (int r = 0; r < 4; ++r) {
                const int row = m0 + mw + mi * 16 + l4 * 4 + r;
                const int col = n0 + nw + ni * 16 + l15;
                Cb[(size_t)row * HW + col] = acc[mi][ni][r] + bias[row];
            }
}

// -------- im2col (bf16, packed-K8) --------
__global__ __launch_bounds__(256)
void im2col_k(const float* __restrict__ Y, u16* __restrict__ col, int sb0)
{
    const int n = blockIdx.x * 256 + threadIdx.x;
    const int kg = blockIdx.y;
    const int sbl = blockIdx.z;
    const float* Yb = Y + (size_t)(sb0 + sbl) * ((size_t)256 * HW);
    const int h = n >> 6, wc = n & 63;
    u16 out[8];
    #pragma unroll
    for (int kl = 0; kl < 8; ++kl) {
        const int k = kg * 8 + kl;
        const int ic = k / 9, r = k - ic * 9;
        const int ih = h + r / 3 - 1, iw = wc + (r % 3) - 1;
        float v = 0.f;
        if (ih >= 0 && ih < 64 && iw >= 0 && iw < 64)
            v = Yb[(size_t)ic * HW + (ih << 6) + iw];
        out[kl] = f2bf(v);
    }
    *(u16x8*)&col[(((size_t)sbl * 288 + kg) * HW + n) * 8] = *(u16x8*)out;
}

// -------- Wd f32 -> bf16 --------
__global__ __launch_bounds__(256)
void cvt_wd_k(const float* __restrict__ Wd, u16* __restrict__ Wh)
{
    const size_t i = ((size_t)blockIdx.x * 256 + threadIdx.x) * 4;
    const float4 v = *(const float4*)&Wd[i];
    u16 o[4] = { f2bf(v.x), f2bf(v.y), f2bf(v.z), f2bf(v.w) };
    *(u16x4*)&Wh[i] = *(u16x4*)o;
}

extern "C" void kernel_launch(void* const* d_in, const int* in_sizes, int n_in,
                              void* d_out, int out_size, void* d_ws, size_t ws_size,
                              hipStream_t stream)
{
    XPtrs xs;
    xs.p[0] = (const float*)d_in[0];
    xs.p[1] = (const float*)d_in[1];
    xs.p[2] = (const float*)d_in[2];
    xs.p[3] = (const float*)d_in[3];
    const float* Wq = (const float*)d_in[4];
    const float* bq = (const float*)d_in[5];
    const float* Wk = (const float*)d_in[6];
    const float* bk = (const float*)d_in[7];
    const float* Wv = (const float*)d_in[8];
    const float* bv = (const float*)d_in[9];
    const float* gp = (const float*)d_in[10];
    const float* gc = (const float*)d_in[11];
    const float* Wd = (const float*)d_in[12];
    const float* bd = (const float*)d_in[13];

    char* base = (char*)d_ws;
    size_t off = 0;
    auto alloc = [&](size_t bytes) -> char* {
        char* p = base + off;
        off = (off + bytes + 255) & ~(size_t)255;
        return p;
    };

    // persistent-through-conv first, overlayable after
    float* Y    = (float*)alloc((size_t)8 * 256 * HW * 4);      // 32 MB
    u16*   Wdh  = (u16*)  alloc((size_t)256 * 2304 * 2);        // 1.1 MB
    const size_t overlayStart = off;
    float* Gp   = (float*)alloc((size_t)8 * 8 * 65536 * 4);     // 16 MB
    float* G    = (float*)alloc((size_t)8 * 65536 * 4);         // 2 MB
    float* att  = (float*)alloc((size_t)2 * 65536 * 4);         // 0.5 MB
    float* Yt   = (float*)alloc((size_t)8 * HW * 256 * 4);      // 32 MB
    u16*   Vh   = (u16*)  alloc((size_t)8 * 256 * HW * 2);      // 16 MB
    float* Qf   = (float*)alloc((size_t)8 * 32 * HW * 4);       // 4 MB
    float* Kf   = (float*)alloc((size_t)8 * 32 * HW * 4);       // 4 MB
    u16*   Qt   = (u16*)  alloc((size_t)8 * HW * 32 * 2);       // 2 MB
    u16*   Kt   = (u16*)  alloc((size_t)8 * HW * 32 * 2);       // 2 MB
    // total fixed ~111.7 MB

    // conv col buffer overlays everything after Y/Wdh (dead by conv time)
    const size_t colPer = (size_t)288 * HW * 8 * 2;             // 18.9 MB / sb
    u16* colp = (u16*)(base + overlayStart);
    long nchunkL = (long)((ws_size - overlayStart) / colPer);
    const int nchunk = (int)(nchunkL > 8 ? 8 : (nchunkL < 1 ? 1 : nchunkL));

    dim3 T(256);

    // Projections: Q, K f32; V bf16
    gemm_k<GM_PROJ><<<dim3(64, 1, 8), T, 0, stream>>>(Wq, nullptr, Qf, bq, nullptr, xs,
                                                      32, 256, 256, HW, HW, 0, 0, 32 * HW);
    gemm_k<GM_PROJ><<<dim3(64, 1, 8), T, 0, stream>>>(Wk, nullptr, Kf, bk, nullptr, xs,
                                                      32, 256, 256, HW, HW, 0, 0, 32 * HW);
    gemm_k<GM_PROJH><<<dim3(64, 4, 8), T, 0, stream>>>(Wv, nullptr, Vh, bv, nullptr, xs,
                                                       256, 256, 256, HW, HW, 0, 0, 256 * HW);
    cvt_wd_k<<<dim3(576), T, 0, stream>>>(Wd, Wdh);

    // transpose Q/K to [n][32] bf16 for flash
    tqk_k<<<dim3(64, 8), T, 0, stream>>>(Qf, Qt);
    tqk_k<<<dim3(64, 8), T, 0, stream>>>(Kf, Kt);

    // CAM: split-K Gram -> reduce -> softmax-sum
    gemm_k<GM_GRAM><<<dim3(4, 4, 64), T, 0, stream>>>(nullptr, nullptr, Gp, nullptr, nullptr, xs,
                                                      256, 512, HW, HW, 256, 0, 0, 65536);
    greduce_k<<<dim3(2048), T, 0, stream>>>(Gp, G);
    cam_softmax_k<<<dim3(256, 2), T, 0, stream>>>(G, att);

    // PAM fused flash: Yt = gp * softmax(Q^T K) @ V^T (transposed layout)
    flash_k<<<dim3(32, 8), dim3(512), 0, stream>>>(Qt, Kt, Vh, Yt, gp);

    // Yt [n][c] -> Y [c][n]
    transT_k<<<dim3(64, 4, 8), T, 0, stream>>>(Yt, Y);

    // CAM apply: Y += gamma_cam * attsum[b] @ X + 5 * X
    gemm_k<GM_CAM><<<dim3(64, 4, 8), T, 0, stream>>>(att, nullptr, Y, nullptr, gc, xs,
                                                     256, 256, 256, HW, HW, 65536, 0, 256 * HW);

    // 3x3 conv: im2col (bf16 packed) + MFMA GEMM, chunked by ws capacity
    for (int c0 = 0; c0 < 8; c0 += nchunk) {
        const int cs = (8 - c0 < nchunk) ? (8 - c0) : nchunk;
        im2col_k<<<dim3(16, 288, cs), T, 0, stream>>>(Y, colp, c0);
        mfma_conv_k<<<dim3(32, 2, cs), T, 0, stream>>>(
            Wdh, colp, (float*)d_out + (size_t)c0 * 256 * HW, bd,
            2304, 2304, (long)288 * HW * 8, (long)256 * HW);
    }
}